// Round 2
// baseline (563.656 us; speedup 1.0000x reference)
//
#include <hip/hip_runtime.h>

#define N_NODES 100000
#define N_EDGES 625000
#define HIDDEN 128
#define NUM_GRAPHS 512
#define CAP 40       // max in-degree capacity; Poisson(6.25) => P(deg>40) ~ e-43
#define PADN 100096  // multiple of 256; 3128 gather-chunks of 32

#define BUILD_BLKS 2443   // ceil(625000/256)
#define EMBED_BLKS 6250   // N_NODES*16/256
#define WT_BLKS 64        // 8 mats x 8 chunks

typedef unsigned int uint;
typedef unsigned short ushort;
typedef short v8s __attribute__((ext_vector_type(8)));
typedef float v16f __attribute__((ext_vector_type(16)));

__device__ __forceinline__ float b2f_lo(uint u) { return __uint_as_float(u << 16); }
__device__ __forceinline__ float b2f_hi(uint u) { return __uint_as_float(u & 0xffff0000u); }
__device__ __forceinline__ uint f2b(float f) {  // RNE f32 -> bf16 bits
  uint u = __float_as_uint(f);
  return (u + 0x7fffu + ((u >> 16) & 1u)) >> 16;
}

// ---------------- fused prep: build adjacency + embed + weight-quantize ----------------
__global__ __launch_bounds__(256) void prep_k(const int* __restrict__ src,
                                              const int* __restrict__ dst,
                                              int* __restrict__ cursor,
                                              int* __restrict__ slots,
                                              const int* __restrict__ x,
                                              const float* __restrict__ emb,
                                              ushort* __restrict__ h,
                                              const float* __restrict__ W1,
                                              const float* __restrict__ W2,
                                              ushort* __restrict__ Wt) {
  int blk = blockIdx.x;
  int tid = threadIdx.x;
  if (blk < BUILD_BLKS) {
    int e = blk * 256 + tid;
    if (e < N_EDGES) {
      int d = dst[e];
      int p = atomicAdd(&cursor[d], 1);
      if (p < CAP) slots[(size_t)d * CAP + p] = src[e];
    }
  } else if (blk < BUILD_BLKS + EMBED_BLKS) {
    int t = (blk - BUILD_BLKS) * 256 + tid;   // one 8-col chunk per thread
    int n = t >> 4;
    if (n < N_NODES) {
      int c = t & 15;
      const float4* e4 = (const float4*)(emb + (size_t)x[n] * HIDDEN + c * 8);
      float4 a = e4[0], b = e4[1];
      uint4 o;
      o.x = f2b(a.x) | (f2b(a.y) << 16);
      o.y = f2b(a.z) | (f2b(a.w) << 16);
      o.z = f2b(b.x) | (f2b(b.y) << 16);
      o.w = f2b(b.z) | (f2b(b.w) << 16);
      ((uint4*)h)[t] = o;
    }
  } else {
    int wb = blk - BUILD_BLKS - EMBED_BLKS;   // 0..63
    int mat = wb >> 3, chunk = wb & 7;
    const float* W = ((mat & 1) ? W2 : W1) + (size_t)(mat >> 1) * 16384;
    ushort* o = Wt + (size_t)mat * 16384;
#pragma unroll
    for (int jj = 0; jj < 8; jj++) {
      int idx = chunk * 2048 + tid + 256 * jj;  // coalesced read W[k][n]
      int k = idx >> 7, n = idx & 127;
      int c = n >> 5, l31 = n & 31;
      int ks = k >> 4, khalf = (k >> 3) & 1, e = k & 7;
      // fragment-ordered: slot s=c*8+ks, lane=khalf*32+l31, elem e
      o[(((c * 8 + ks) << 6) + (khalf << 5) + l31) * 8 + e] = (ushort)f2b(W[idx]);
    }
  }
}

// ---------------- degree-grouped permutation, two-level (LDS-aggregated) ----------------
__global__ __launch_bounds__(256) void hist_k(const int* __restrict__ cursor,
                                              int* __restrict__ bins) {
  __shared__ int lb[CAP + 1];
  int tid = threadIdx.x;
  if (tid <= CAP) lb[tid] = 0;
  __syncthreads();
  int n = blockIdx.x * 256 + tid;
  if (n < N_NODES) {
    int d = cursor[n]; if (d > CAP) d = CAP;
    atomicAdd(&lb[d], 1);                     // LDS atomic: cheap
  }
  __syncthreads();
  if (tid <= CAP && lb[tid] > 0) atomicAdd(&bins[tid], lb[tid]);  // fire-and-forget
}

__global__ __launch_bounds__(64) void scan_k(int* __restrict__ bins) {
  int i = threadIdx.x;
  int c = (i <= CAP) ? bins[i] : 0;
  int incl = c;
#pragma unroll
  for (int off = 1; off < 64; off <<= 1) {
    int t = __shfl_up(incl, off, 64);
    if (i >= off) incl += t;
  }
  if (i <= CAP) bins[i] = incl - c;           // exclusive prefix
}

// LPT dispatch: perm REVERSED (descending degree) so deg-40 blocks launch first.
__global__ __launch_bounds__(256) void scatter_k(const int* __restrict__ cursor,
                                                 int* __restrict__ bins,
                                                 int* __restrict__ perm) {
  __shared__ int lb[CAP + 1];
  __shared__ int lbase[CAP + 1];
  int tid = threadIdx.x;
  if (tid <= CAP) lb[tid] = 0;
  __syncthreads();
  int n = blockIdx.x * 256 + tid;
  int d = 0, rank = 0;
  bool real = (n < N_NODES);
  if (real) {
    d = cursor[n]; if (d > CAP) d = CAP;
    rank = atomicAdd(&lb[d], 1);
  }
  __syncthreads();
  if (tid <= CAP) {
    int c = lb[tid];
    lbase[tid] = c > 0 ? atomicAdd(&bins[tid], c) : 0;
  }
  __syncthreads();
  if (real) perm[(N_NODES - 1) - (lbase[d] + rank)] = n;   // descending degree
  else if (n < PADN) perm[n] = 0;
}

// ---------------- fused layer: h_out = (relu((agg+h)@W1+b1))@W2 + b2 ----------------
// R12: TWO waves per 32-row tile (128 thr). Wave0 gathers self + even-index
// neighbors, wave1 odd-index neighbors; f32 partials reduced via 16KB LDS
// (skipped block-uniformly when all deg<=1). Slot indices prefetched as int4
// chunks ahead (clamped to chunk 9 so reads never leave the node's 40-int
// row — no workspace pad needed). Wave0 then runs the proven GEMM path.
union U { uint4 u; v8s s; };

__device__ __forceinline__ void loadrow(uint4 dst[8], const uint4* __restrict__ rowp,
                                        int khalf) {
#pragma unroll
  for (int ks = 0; ks < 8; ks++) dst[ks] = rowp[khalf + 2 * ks];
}

__device__ __forceinline__ void accum8(const uint4 u[8], float acc[8][8]) {
#pragma unroll
  for (int ks = 0; ks < 8; ks++) {
    acc[ks][0] += b2f_lo(u[ks].x); acc[ks][1] += b2f_hi(u[ks].x);
    acc[ks][2] += b2f_lo(u[ks].y); acc[ks][3] += b2f_hi(u[ks].y);
    acc[ks][4] += b2f_lo(u[ks].z); acc[ks][5] += b2f_hi(u[ks].z);
    acc[ks][6] += b2f_lo(u[ks].w); acc[ks][7] += b2f_hi(u[ks].w);
  }
}

__global__ __launch_bounds__(128, 4) void layer_k(const ushort* __restrict__ hin,
                                                  const int* __restrict__ cursor,
                                                  const int* __restrict__ slots,
                                                  const int* __restrict__ perm,
                                                  const ushort* __restrict__ W1f,
                                                  const ushort* __restrict__ W2f,
                                                  const float* __restrict__ b1,
                                                  const float* __restrict__ b2,
                                                  ushort* __restrict__ hout) {
  __shared__ float red[64 * 64];              // 16KB reduce buffer (element-major)
  int tid = threadIdx.x;
  int wid = tid >> 6;                         // 0: self+even nbrs + GEMM; 1: odd nbrs
  int lane = tid & 63;
  int l31 = lane & 31;
  int khalf = lane >> 5;
  int tb = blockIdx.x * 32;                   // tile base in perm order
  int prow = perm[tb + l31];                  // true row this lane gathers
  bool valid = (tb + l31) < N_NODES;

  float acc[8][8];
#pragma unroll
  for (int ks = 0; ks < 8; ks++)
#pragma unroll
    for (int e = 0; e < 8; e++) acc[ks][e] = 0.f;

  const uint4* base = (const uint4*)hin;      // 16 uint4 per 128-col row
  uint4 A[8], B[8];

  int deg = valid ? cursor[prow] : 0;
  if (deg > CAP) deg = CAP;
  // block-uniform decision: both waves see identical per-lane deg values
  bool need2 = __ballot(deg > 1) != 0ull;

  const int4* slv = (const int4*)(slots + (size_t)prow * CAP);  // exactly 10 int4
  int mg = (deg - wid + 1) >> 1;              // neighbor rows this wave gathers
  int4 ck = slv[0];                           // slots 0..3
  int4 cn = slv[1];                           // slots 4..7 (prefetch)

  if (wid == 0) {
    loadrow(A, base + (size_t)prow * 16, khalf);               // self -> A
    if (mg > 0) loadrow(B, base + (size_t)ck.x * 16, khalf);   // nbr j=0 -> B
    __builtin_amdgcn_sched_barrier(0);
    accum8(A, acc);                                            // self
  } else {
    if (mg > 0) loadrow(B, base + (size_t)ck.y * 16, khalf);   // nbr j=1 -> B
    __builtin_amdgcn_sched_barrier(0);
  }

  // local row i covers global neighbor j = 2i+wid; chunk = i>>1,
  // component = wid + 2*(i&1). Depth-2 A/B ping-pong, chunks prefetched ahead.
  int i = 0;
  while (i + 2 <= mg) {
    int sA = wid ? ck.w : ck.z;                                // local row i+1
    loadrow(A, base + (size_t)sA * 16, khalf);
    __builtin_amdgcn_sched_barrier(0);
    accum8(B, acc);                                            // local row i
    int cidx = (i >> 1) + 2;                                   // prefetch chunk
    if (cidx > 9) cidx = 9;                                    // stay inside row
    int4 nx = slv[cidx];
    if (i + 2 < mg) {
      int sB = wid ? cn.y : cn.x;                              // local row i+2
      loadrow(B, base + (size_t)sB * 16, khalf);
    }
    __builtin_amdgcn_sched_barrier(0);
    accum8(A, acc);                                            // local row i+1
    ck = cn; cn = nx;
    i += 2;
  }
  if (i < mg) accum8(B, acc);                                  // last odd local row

  // ---- cross-wave f32 reduction (only when wave1 actually gathered) ----
  if (need2) {
    if (wid == 1) {
#pragma unroll
      for (int ks = 0; ks < 8; ks++)
#pragma unroll
        for (int e = 0; e < 8; e++)
          red[(ks * 8 + e) * 64 + lane] = acc[ks][e];
    }
    __syncthreads();
    if (wid == 0) {
#pragma unroll
      for (int ks = 0; ks < 8; ks++)
#pragma unroll
        for (int e = 0; e < 8; e++)
          acc[ks][e] += red[(ks * 8 + e) * 64 + lane];
    }
  }
  if (wid == 1) return;                        // wave1 done (no further barriers)

  // round to bf16 A-frags (same rounding point as unfused t0 = bf16(agg+h))
  U afr[8];
#pragma unroll
  for (int ks = 0; ks < 8; ks++) {
    afr[ks].u.x = f2b(acc[ks][0]) | (f2b(acc[ks][1]) << 16);
    afr[ks].u.y = f2b(acc[ks][2]) | (f2b(acc[ks][3]) << 16);
    afr[ks].u.z = f2b(acc[ks][4]) | (f2b(acc[ks][5]) << 16);
    afr[ks].u.w = f2b(acc[ks][6]) | (f2b(acc[ks][7]) << 16);
  }

  // ---- GEMM1 (flipped): z^T = W1^T-as-A @ agg-as-B; lane = node row ----
  const uint4* W1v = (const uint4*)W1f;       // frag-ordered: slot*64 + lane
  v16f acc1[4] = {};
#pragma unroll
  for (int c = 0; c < 4; c++)
#pragma unroll
    for (int ks = 0; ks < 8; ks++) {
      U b; b.u = W1v[((c * 8 + ks) << 6) + lane];
      acc1[c] = __builtin_amdgcn_mfma_f32_32x32x16_bf16(b.s, afr[ks].s, acc1[c], 0, 0, 0);
    }

  // bias + relu + pack: lane holds z[r=l31][k'], k' = 32c + (reg&3) + 8*(reg>>2) + 4*khalf
  uint u[4][4][2];
#pragma unroll
  for (int c = 0; c < 4; c++)
#pragma unroll
    for (int b = 0; b < 4; b++)
#pragma unroll
      for (int ap = 0; ap < 2; ap++) {
        int r0 = 2 * ap + 4 * b, r1 = r0 + 1;
        float v0 = fmaxf(acc1[c][r0] + b1[c * 32 + 2 * ap + 8 * b + 4 * khalf], 0.f);
        float v1 = fmaxf(acc1[c][r1] + b1[c * 32 + 2 * ap + 1 + 8 * b + 4 * khalf], 0.f);
        u[c][b][ap] = f2b(v0) | (f2b(v1) << 16);
      }

  uint got[4][2][2];
#pragma unroll
  for (int c = 0; c < 4; c++)
#pragma unroll
    for (int bh = 0; bh < 2; bh++)
#pragma unroll
      for (int ap = 0; ap < 2; ap++) {
        uint send = khalf ? u[c][2 * bh][ap] : u[c][2 * bh + 1][ap];
        got[c][bh][ap] = __shfl_xor(send, 32, 64);
      }

  U az[8];
#pragma unroll
  for (int ks = 0; ks < 8; ks++) {
    uint o0 = khalf ? u[ks >> 1][2 * (ks & 1) + 1][0] : u[ks >> 1][2 * (ks & 1)][0];
    uint o1 = khalf ? u[ks >> 1][2 * (ks & 1) + 1][1] : u[ks >> 1][2 * (ks & 1)][1];
    uint g0 = got[ks >> 1][ks & 1][0];
    uint g1 = got[ks >> 1][ks & 1][1];
    az[ks].u.x = khalf ? g0 : o0;
    az[ks].u.y = khalf ? g1 : o1;
    az[ks].u.z = khalf ? o0 : g0;
    az[ks].u.w = khalf ? o1 : g1;
  }

  // ---- GEMM2 (normal): h_out = z @ W2 + b2 ----
  const uint4* W2v = (const uint4*)W2f;
  v16f acc2[4] = {};
#pragma unroll
  for (int c = 0; c < 4; c++)
#pragma unroll
    for (int ks = 0; ks < 8; ks++) {
      U b; b.u = W2v[((c * 8 + ks) << 6) + lane];
      acc2[c] = __builtin_amdgcn_mfma_f32_32x32x16_bf16(az[ks].s, b.s, acc2[c], 0, 0, 0);
    }

  int trow[16];
#pragma unroll
  for (int r = 0; r < 16; r++) {
    int m = (r & 3) + 8 * (r >> 2) + 4 * khalf;
    trow[r] = __shfl(prow, m, 64);
  }
  float bv2[4];
#pragma unroll
  for (int c = 0; c < 4; c++) bv2[c] = b2[c * 32 + l31];
#pragma unroll
  for (int c = 0; c < 4; c++) {
    int col = c * 32 + l31;
#pragma unroll
    for (int r = 0; r < 16; r++) {
      int m = (r & 3) + 8 * (r >> 2) + 4 * khalf;
      if (tb + m < N_NODES)
        hout[(size_t)trow[r] * HIDDEN + col] = (ushort)f2b(acc2[c][r] + bv2[c]);
    }
  }
}

// ---------------- fused pool+MLP: g = segsum(h); out = mlp(g) ----------------
__global__ __launch_bounds__(256) void poolmlp_k(const ushort* __restrict__ h,
                                                 const int* __restrict__ batch,
                                                 const float* __restrict__ W1, const float* __restrict__ b1,
                                                 const float* __restrict__ W2, const float* __restrict__ b2,
                                                 const float* __restrict__ W3, const float* __restrict__ b3,
                                                 float* __restrict__ out) {
  __shared__ int se[2];
  __shared__ float red[16][16][8];
  __shared__ float gl[128];
  __shared__ float r2[64];
  __shared__ float r3[32];
  int gi = blockIdx.x, tid = threadIdx.x;
  if (tid < 2) {
    int target = gi + tid;
    int lo = 0, hi = N_NODES;
    while (lo < hi) {
      int mid = (lo + hi) >> 1;
      if (batch[mid] < target) lo = mid + 1; else hi = mid;
    }
    se[tid] = lo;
  }
  __syncthreads();
  int start = se[0], end = se[1];
  int cg = tid & 15, rg = tid >> 4;
  float acc[8] = {0.f, 0.f, 0.f, 0.f, 0.f, 0.f, 0.f, 0.f};
  for (int r = start + rg; r < end; r += 16) {
    uint4 v = ((const uint4*)h)[r * 16 + cg];
    acc[0] += b2f_lo(v.x); acc[1] += b2f_hi(v.x);
    acc[2] += b2f_lo(v.y); acc[3] += b2f_hi(v.y);
    acc[4] += b2f_lo(v.z); acc[5] += b2f_hi(v.z);
    acc[6] += b2f_lo(v.w); acc[7] += b2f_hi(v.w);
  }
#pragma unroll
  for (int j = 0; j < 8; j++) red[rg][cg][j] = acc[j];
  __syncthreads();
  if (rg == 0) {
    float s[8];
#pragma unroll
    for (int j = 0; j < 8; j++) s[j] = red[0][cg][j];
#pragma unroll
    for (int i = 1; i < 16; i++)
#pragma unroll
      for (int j = 0; j < 8; j++) s[j] += red[i][cg][j];
#pragma unroll
    for (int j = 0; j < 8; j++) gl[cg * 8 + j] = s[j];
  }
  __syncthreads();
  if (tid < 64) {
    float s = b1[tid];
    for (int k = 0; k < 128; k++) s = fmaf(gl[k], W1[k * 64 + tid], s);
    r2[tid] = fmaxf(s, 0.f);
  }
  __syncthreads();
  if (tid < 32) {
    float s2 = b2[tid];
    for (int k = 0; k < 64; k++) s2 = fmaf(r2[k], W2[k * 32 + tid], s2);
    r3[tid] = fmaxf(s2, 0.f);
  }
  __syncthreads();
  if (tid < 64) {
    float pv = (tid < 32) ? r3[tid] * W3[tid] : 0.f;
#pragma unroll
    for (int off = 32; off > 0; off >>= 1) pv += __shfl_down(pv, off);
    if (tid == 0) out[gi] = pv + b3[0];
  }
}

extern "C" void kernel_launch(void* const* d_in, const int* in_sizes, int n_in,
                              void* d_out, int out_size, void* d_ws, size_t ws_size,
                              hipStream_t stream) {
  const int* x = (const int*)d_in[0];
  const int* src = (const int*)d_in[1];
  const int* dst = src + N_EDGES;
  const int* batch = (const int*)d_in[3];
  const float* node_emb = (const float*)d_in[4];
  const float* cW1 = (const float*)d_in[6];
  const float* cb1 = (const float*)d_in[7];
  const float* cW2 = (const float*)d_in[8];
  const float* cb2 = (const float*)d_in[9];
  const float* mW1 = (const float*)d_in[10];
  const float* mb1 = (const float*)d_in[11];
  const float* mW2 = (const float*)d_in[12];
  const float* mb2 = (const float*)d_in[13];
  const float* mW3 = (const float*)d_in[14];
  const float* mb3 = (const float*)d_in[15];
  float* out = (float*)d_out;

  char* p = (char*)d_ws;
  const size_t HB = (size_t)N_NODES * HIDDEN * sizeof(ushort);  // 25.6 MB
  ushort* h = (ushort*)p;      p += HB;
  ushort* t0 = (ushort*)p;     p += HB;
  ushort* Wtb = (ushort*)p;    p += (size_t)8 * 16384 * sizeof(ushort);
  int* cursor = (int*)p;       p += (size_t)N_NODES * sizeof(int);
  int* bins = (int*)p;         p += 64 * sizeof(int);
  int* slots = (int*)p;        p += (size_t)N_NODES * CAP * sizeof(int);
  int* perm = (int*)p;         p += (size_t)PADN * sizeof(int);

  (void)hipMemsetAsync(cursor, 0, ((size_t)N_NODES + 64) * sizeof(int), stream);  // cursor + bins
  prep_k<<<BUILD_BLKS + EMBED_BLKS + WT_BLKS, 256, 0, stream>>>(
      src, dst, cursor, slots, x, node_emb, h, cW1, cW2, Wtb);
  hist_k<<<PADN / 256, 256, 0, stream>>>(cursor, bins);
  scan_k<<<1, 64, 0, stream>>>(bins);
  scatter_k<<<PADN / 256, 256, 0, stream>>>(cursor, bins, perm);

  const int grid = PADN / 32;  // 3128 tiles, 2 waves each
  ushort* bufs[2] = {h, t0};
  for (int l = 0; l < 4; l++) {
    layer_k<<<grid, 128, 0, stream>>>(bufs[l & 1], cursor, slots, perm,
                                      Wtb + (size_t)(2 * l) * 16384,
                                      Wtb + (size_t)(2 * l + 1) * 16384,
                                      cb1 + (size_t)l * HIDDEN,
                                      cb2 + (size_t)l * HIDDEN,
                                      bufs[(l & 1) ^ 1]);
  }
  // after 4 layers output is back in h (bufs[0])
  poolmlp_k<<<NUM_GRAPHS, 256, 0, stream>>>(h, batch, mW1, mb1, mW2, mb2, mW3, mb3, out);
}

// Round 3
// 370.570 us; speedup vs baseline: 1.5211x; 1.5211x over previous
//
#include <hip/hip_runtime.h>

#define N_NODES 100000
#define N_EDGES 625000
#define HIDDEN 128
#define NUM_GRAPHS 512
#define CAP 40       // max in-degree capacity; Poisson(6.25) => P(deg>40) ~ e-43
#define PADN 100096  // multiple of 256; 3128 gather-chunks of 32

#define BUILD_BLKS 2443   // ceil(625000/256)
#define EMBED_BLKS 6250   // N_NODES*16/256
#define WT_BLKS 64        // 8 mats x 8 chunks

typedef unsigned int uint;
typedef unsigned short ushort;
typedef short v8s __attribute__((ext_vector_type(8)));
typedef float v16f __attribute__((ext_vector_type(16)));

__device__ __forceinline__ float b2f_lo(uint u) { return __uint_as_float(u << 16); }
__device__ __forceinline__ float b2f_hi(uint u) { return __uint_as_float(u & 0xffff0000u); }
__device__ __forceinline__ uint f2b(float f) {  // RNE f32 -> bf16 bits
  uint u = __float_as_uint(f);
  return (u + 0x7fffu + ((u >> 16) & 1u)) >> 16;
}

// ---------------- fused prep: build adjacency + embed + weight-quantize ----------------
__global__ __launch_bounds__(256) void prep_k(const int* __restrict__ src,
                                              const int* __restrict__ dst,
                                              int* __restrict__ cursor,
                                              int* __restrict__ slots,
                                              const int* __restrict__ x,
                                              const float* __restrict__ emb,
                                              ushort* __restrict__ h,
                                              const float* __restrict__ W1,
                                              const float* __restrict__ W2,
                                              ushort* __restrict__ Wt) {
  int blk = blockIdx.x;
  int tid = threadIdx.x;
  if (blk < BUILD_BLKS) {
    int e = blk * 256 + tid;
    if (e < N_EDGES) {
      int d = dst[e];
      int p = atomicAdd(&cursor[d], 1);
      if (p < CAP) slots[(size_t)d * CAP + p] = src[e];
    }
  } else if (blk < BUILD_BLKS + EMBED_BLKS) {
    int t = (blk - BUILD_BLKS) * 256 + tid;   // one 8-col chunk per thread
    int n = t >> 4;
    if (n < N_NODES) {
      int c = t & 15;
      const float4* e4 = (const float4*)(emb + (size_t)x[n] * HIDDEN + c * 8);
      float4 a = e4[0], b = e4[1];
      uint4 o;
      o.x = f2b(a.x) | (f2b(a.y) << 16);
      o.y = f2b(a.z) | (f2b(a.w) << 16);
      o.z = f2b(b.x) | (f2b(b.y) << 16);
      o.w = f2b(b.z) | (f2b(b.w) << 16);
      ((uint4*)h)[t] = o;
    }
  } else {
    int wb = blk - BUILD_BLKS - EMBED_BLKS;   // 0..63
    int mat = wb >> 3, chunk = wb & 7;
    const float* W = ((mat & 1) ? W2 : W1) + (size_t)(mat >> 1) * 16384;
    ushort* o = Wt + (size_t)mat * 16384;
#pragma unroll
    for (int jj = 0; jj < 8; jj++) {
      int idx = chunk * 2048 + tid + 256 * jj;  // coalesced read W[k][n]
      int k = idx >> 7, n = idx & 127;
      int c = n >> 5, l31 = n & 31;
      int ks = k >> 4, khalf = (k >> 3) & 1, e = k & 7;
      // fragment-ordered: slot s=c*8+ks, lane=khalf*32+l31, elem e
      o[(((c * 8 + ks) << 6) + (khalf << 5) + l31) * 8 + e] = (ushort)f2b(W[idx]);
    }
  }
}

// ---------------- degree-grouped permutation, two-level (LDS-aggregated) ----------------
__global__ __launch_bounds__(256) void hist_k(const int* __restrict__ cursor,
                                              int* __restrict__ bins) {
  __shared__ int lb[CAP + 1];
  int tid = threadIdx.x;
  if (tid <= CAP) lb[tid] = 0;
  __syncthreads();
  int n = blockIdx.x * 256 + tid;
  if (n < N_NODES) {
    int d = cursor[n]; if (d > CAP) d = CAP;
    atomicAdd(&lb[d], 1);                     // LDS atomic: cheap
  }
  __syncthreads();
  if (tid <= CAP && lb[tid] > 0) atomicAdd(&bins[tid], lb[tid]);  // fire-and-forget
}

__global__ __launch_bounds__(64) void scan_k(int* __restrict__ bins) {
  int i = threadIdx.x;
  int c = (i <= CAP) ? bins[i] : 0;
  int incl = c;
#pragma unroll
  for (int off = 1; off < 64; off <<= 1) {
    int t = __shfl_up(incl, off, 64);
    if (i >= off) incl += t;
  }
  if (i <= CAP) bins[i] = incl - c;           // exclusive prefix
}

// LPT dispatch: perm REVERSED (descending degree) so deg-40 blocks launch first.
__global__ __launch_bounds__(256) void scatter_k(const int* __restrict__ cursor,
                                                 int* __restrict__ bins,
                                                 int* __restrict__ perm) {
  __shared__ int lb[CAP + 1];
  __shared__ int lbase[CAP + 1];
  int tid = threadIdx.x;
  if (tid <= CAP) lb[tid] = 0;
  __syncthreads();
  int n = blockIdx.x * 256 + tid;
  int d = 0, rank = 0;
  bool real = (n < N_NODES);
  if (real) {
    d = cursor[n]; if (d > CAP) d = CAP;
    rank = atomicAdd(&lb[d], 1);
  }
  __syncthreads();
  if (tid <= CAP) {
    int c = lb[tid];
    lbase[tid] = c > 0 ? atomicAdd(&bins[tid], c) : 0;
  }
  __syncthreads();
  if (real) perm[(N_NODES - 1) - (lbase[d] + rank)] = n;   // descending degree
  else if (n < PADN) perm[n] = 0;
}

// ---------------- fused layer: h_out = (relu((agg+h)@W1+b1))@W2 + b2 ----------------
// R13: identical to R12 except __launch_bounds__(128, 3). R12's (128,4) capped
// combined VGPR+AGPR at 128/wave; the kernel needs ~170 (84 VGPR gather + 64-86
// AGPR MFMA accum, proven by the 64-thread baseline at (64,3)) -> allocator
// spilled acc to scratch (WRITE_SIZE 28->172MB, dur 50->108us). (128,3) restores
// the 170-reg budget; occupancy register-capped at 3 waves/SIMD but SUSTAINED
// (6256 grid waves vs 3128), with per-wave gather chain halved.
union U { uint4 u; v8s s; };

__device__ __forceinline__ void loadrow(uint4 dst[8], const uint4* __restrict__ rowp,
                                        int khalf) {
#pragma unroll
  for (int ks = 0; ks < 8; ks++) dst[ks] = rowp[khalf + 2 * ks];
}

__device__ __forceinline__ void accum8(const uint4 u[8], float acc[8][8]) {
#pragma unroll
  for (int ks = 0; ks < 8; ks++) {
    acc[ks][0] += b2f_lo(u[ks].x); acc[ks][1] += b2f_hi(u[ks].x);
    acc[ks][2] += b2f_lo(u[ks].y); acc[ks][3] += b2f_hi(u[ks].y);
    acc[ks][4] += b2f_lo(u[ks].z); acc[ks][5] += b2f_hi(u[ks].z);
    acc[ks][6] += b2f_lo(u[ks].w); acc[ks][7] += b2f_hi(u[ks].w);
  }
}

__global__ __launch_bounds__(128, 3) void layer_k(const ushort* __restrict__ hin,
                                                  const int* __restrict__ cursor,
                                                  const int* __restrict__ slots,
                                                  const int* __restrict__ perm,
                                                  const ushort* __restrict__ W1f,
                                                  const ushort* __restrict__ W2f,
                                                  const float* __restrict__ b1,
                                                  const float* __restrict__ b2,
                                                  ushort* __restrict__ hout) {
  __shared__ float red[64 * 64];              // 16KB reduce buffer (element-major)
  int tid = threadIdx.x;
  int wid = tid >> 6;                         // 0: self+even nbrs + GEMM; 1: odd nbrs
  int lane = tid & 63;
  int l31 = lane & 31;
  int khalf = lane >> 5;
  int tb = blockIdx.x * 32;                   // tile base in perm order
  int prow = perm[tb + l31];                  // true row this lane gathers
  bool valid = (tb + l31) < N_NODES;

  float acc[8][8];
#pragma unroll
  for (int ks = 0; ks < 8; ks++)
#pragma unroll
    for (int e = 0; e < 8; e++) acc[ks][e] = 0.f;

  const uint4* base = (const uint4*)hin;      // 16 uint4 per 128-col row
  uint4 A[8], B[8];

  int deg = valid ? cursor[prow] : 0;
  if (deg > CAP) deg = CAP;
  // block-uniform decision: both waves see identical per-lane deg values
  bool need2 = __ballot(deg > 1) != 0ull;

  const int4* slv = (const int4*)(slots + (size_t)prow * CAP);  // exactly 10 int4
  int mg = (deg - wid + 1) >> 1;              // neighbor rows this wave gathers
  int4 ck = slv[0];                           // slots 0..3
  int4 cn = slv[1];                           // slots 4..7 (prefetch)

  if (wid == 0) {
    loadrow(A, base + (size_t)prow * 16, khalf);               // self -> A
    if (mg > 0) loadrow(B, base + (size_t)ck.x * 16, khalf);   // nbr j=0 -> B
    __builtin_amdgcn_sched_barrier(0);
    accum8(A, acc);                                            // self
  } else {
    if (mg > 0) loadrow(B, base + (size_t)ck.y * 16, khalf);   // nbr j=1 -> B
    __builtin_amdgcn_sched_barrier(0);
  }

  // local row i covers global neighbor j = 2i+wid; chunk = i>>1,
  // component = wid + 2*(i&1). Depth-2 A/B ping-pong, chunks prefetched ahead.
  int i = 0;
  while (i + 2 <= mg) {
    int sA = wid ? ck.w : ck.z;                                // local row i+1
    loadrow(A, base + (size_t)sA * 16, khalf);
    __builtin_amdgcn_sched_barrier(0);
    accum8(B, acc);                                            // local row i
    int cidx = (i >> 1) + 2;                                   // prefetch chunk
    if (cidx > 9) cidx = 9;                                    // stay inside row
    int4 nx = slv[cidx];
    if (i + 2 < mg) {
      int sB = wid ? cn.y : cn.x;                              // local row i+2
      loadrow(B, base + (size_t)sB * 16, khalf);
    }
    __builtin_amdgcn_sched_barrier(0);
    accum8(A, acc);                                            // local row i+1
    ck = cn; cn = nx;
    i += 2;
  }
  if (i < mg) accum8(B, acc);                                  // last odd local row

  // ---- cross-wave f32 reduction (only when wave1 actually gathered) ----
  if (need2) {
    if (wid == 1) {
#pragma unroll
      for (int ks = 0; ks < 8; ks++)
#pragma unroll
        for (int e = 0; e < 8; e++)
          red[(ks * 8 + e) * 64 + lane] = acc[ks][e];
    }
    __syncthreads();
    if (wid == 0) {
#pragma unroll
      for (int ks = 0; ks < 8; ks++)
#pragma unroll
        for (int e = 0; e < 8; e++)
          acc[ks][e] += red[(ks * 8 + e) * 64 + lane];
    }
  }
  if (wid == 1) return;                        // wave1 done (no further barriers)

  // round to bf16 A-frags (same rounding point as unfused t0 = bf16(agg+h))
  U afr[8];
#pragma unroll
  for (int ks = 0; ks < 8; ks++) {
    afr[ks].u.x = f2b(acc[ks][0]) | (f2b(acc[ks][1]) << 16);
    afr[ks].u.y = f2b(acc[ks][2]) | (f2b(acc[ks][3]) << 16);
    afr[ks].u.z = f2b(acc[ks][4]) | (f2b(acc[ks][5]) << 16);
    afr[ks].u.w = f2b(acc[ks][6]) | (f2b(acc[ks][7]) << 16);
  }

  // ---- GEMM1 (flipped): z^T = W1^T-as-A @ agg-as-B; lane = node row ----
  const uint4* W1v = (const uint4*)W1f;       // frag-ordered: slot*64 + lane
  v16f acc1[4] = {};
#pragma unroll
  for (int c = 0; c < 4; c++)
#pragma unroll
    for (int ks = 0; ks < 8; ks++) {
      U b; b.u = W1v[((c * 8 + ks) << 6) + lane];
      acc1[c] = __builtin_amdgcn_mfma_f32_32x32x16_bf16(b.s, afr[ks].s, acc1[c], 0, 0, 0);
    }

  // bias + relu + pack: lane holds z[r=l31][k'], k' = 32c + (reg&3) + 8*(reg>>2) + 4*khalf
  uint u[4][4][2];
#pragma unroll
  for (int c = 0; c < 4; c++)
#pragma unroll
    for (int b = 0; b < 4; b++)
#pragma unroll
      for (int ap = 0; ap < 2; ap++) {
        int r0 = 2 * ap + 4 * b, r1 = r0 + 1;
        float v0 = fmaxf(acc1[c][r0] + b1[c * 32 + 2 * ap + 8 * b + 4 * khalf], 0.f);
        float v1 = fmaxf(acc1[c][r1] + b1[c * 32 + 2 * ap + 1 + 8 * b + 4 * khalf], 0.f);
        u[c][b][ap] = f2b(v0) | (f2b(v1) << 16);
      }

  uint got[4][2][2];
#pragma unroll
  for (int c = 0; c < 4; c++)
#pragma unroll
    for (int bh = 0; bh < 2; bh++)
#pragma unroll
      for (int ap = 0; ap < 2; ap++) {
        uint send = khalf ? u[c][2 * bh][ap] : u[c][2 * bh + 1][ap];
        got[c][bh][ap] = __shfl_xor(send, 32, 64);
      }

  U az[8];
#pragma unroll
  for (int ks = 0; ks < 8; ks++) {
    uint o0 = khalf ? u[ks >> 1][2 * (ks & 1) + 1][0] : u[ks >> 1][2 * (ks & 1)][0];
    uint o1 = khalf ? u[ks >> 1][2 * (ks & 1) + 1][1] : u[ks >> 1][2 * (ks & 1)][1];
    uint g0 = got[ks >> 1][ks & 1][0];
    uint g1 = got[ks >> 1][ks & 1][1];
    az[ks].u.x = khalf ? g0 : o0;
    az[ks].u.y = khalf ? g1 : o1;
    az[ks].u.z = khalf ? o0 : g0;
    az[ks].u.w = khalf ? o1 : g1;
  }

  // ---- GEMM2 (normal): h_out = z @ W2 + b2 ----
  const uint4* W2v = (const uint4*)W2f;
  v16f acc2[4] = {};
#pragma unroll
  for (int c = 0; c < 4; c++)
#pragma unroll
    for (int ks = 0; ks < 8; ks++) {
      U b; b.u = W2v[((c * 8 + ks) << 6) + lane];
      acc2[c] = __builtin_amdgcn_mfma_f32_32x32x16_bf16(az[ks].s, b.s, acc2[c], 0, 0, 0);
    }

  int trow[16];
#pragma unroll
  for (int r = 0; r < 16; r++) {
    int m = (r & 3) + 8 * (r >> 2) + 4 * khalf;
    trow[r] = __shfl(prow, m, 64);
  }
  float bv2[4];
#pragma unroll
  for (int c = 0; c < 4; c++) bv2[c] = b2[c * 32 + l31];
#pragma unroll
  for (int c = 0; c < 4; c++) {
    int col = c * 32 + l31;
#pragma unroll
    for (int r = 0; r < 16; r++) {
      int m = (r & 3) + 8 * (r >> 2) + 4 * khalf;
      if (tb + m < N_NODES)
        hout[(size_t)trow[r] * HIDDEN + col] = (ushort)f2b(acc2[c][r] + bv2[c]);
    }
  }
}

// ---------------- fused pool+MLP: g = segsum(h); out = mlp(g) ----------------
__global__ __launch_bounds__(256) void poolmlp_k(const ushort* __restrict__ h,
                                                 const int* __restrict__ batch,
                                                 const float* __restrict__ W1, const float* __restrict__ b1,
                                                 const float* __restrict__ W2, const float* __restrict__ b2,
                                                 const float* __restrict__ W3, const float* __restrict__ b3,
                                                 float* __restrict__ out) {
  __shared__ int se[2];
  __shared__ float red[16][16][8];
  __shared__ float gl[128];
  __shared__ float r2[64];
  __shared__ float r3[32];
  int gi = blockIdx.x, tid = threadIdx.x;
  if (tid < 2) {
    int target = gi + tid;
    int lo = 0, hi = N_NODES;
    while (lo < hi) {
      int mid = (lo + hi) >> 1;
      if (batch[mid] < target) lo = mid + 1; else hi = mid;
    }
    se[tid] = lo;
  }
  __syncthreads();
  int start = se[0], end = se[1];
  int cg = tid & 15, rg = tid >> 4;
  float acc[8] = {0.f, 0.f, 0.f, 0.f, 0.f, 0.f, 0.f, 0.f};
  for (int r = start + rg; r < end; r += 16) {
    uint4 v = ((const uint4*)h)[r * 16 + cg];
    acc[0] += b2f_lo(v.x); acc[1] += b2f_hi(v.x);
    acc[2] += b2f_lo(v.y); acc[3] += b2f_hi(v.y);
    acc[4] += b2f_lo(v.z); acc[5] += b2f_hi(v.z);
    acc[6] += b2f_lo(v.w); acc[7] += b2f_hi(v.w);
  }
#pragma unroll
  for (int j = 0; j < 8; j++) red[rg][cg][j] = acc[j];
  __syncthreads();
  if (rg == 0) {
    float s[8];
#pragma unroll
    for (int j = 0; j < 8; j++) s[j] = red[0][cg][j];
#pragma unroll
    for (int i = 1; i < 16; i++)
#pragma unroll
      for (int j = 0; j < 8; j++) s[j] += red[i][cg][j];
#pragma unroll
    for (int j = 0; j < 8; j++) gl[cg * 8 + j] = s[j];
  }
  __syncthreads();
  if (tid < 64) {
    float s = b1[tid];
    for (int k = 0; k < 128; k++) s = fmaf(gl[k], W1[k * 64 + tid], s);
    r2[tid] = fmaxf(s, 0.f);
  }
  __syncthreads();
  if (tid < 32) {
    float s2 = b2[tid];
    for (int k = 0; k < 64; k++) s2 = fmaf(r2[k], W2[k * 32 + tid], s2);
    r3[tid] = fmaxf(s2, 0.f);
  }
  __syncthreads();
  if (tid < 64) {
    float pv = (tid < 32) ? r3[tid] * W3[tid] : 0.f;
#pragma unroll
    for (int off = 32; off > 0; off >>= 1) pv += __shfl_down(pv, off);
    if (tid == 0) out[gi] = pv + b3[0];
  }
}

extern "C" void kernel_launch(void* const* d_in, const int* in_sizes, int n_in,
                              void* d_out, int out_size, void* d_ws, size_t ws_size,
                              hipStream_t stream) {
  const int* x = (const int*)d_in[0];
  const int* src = (const int*)d_in[1];
  const int* dst = src + N_EDGES;
  const int* batch = (const int*)d_in[3];
  const float* node_emb = (const float*)d_in[4];
  const float* cW1 = (const float*)d_in[6];
  const float* cb1 = (const float*)d_in[7];
  const float* cW2 = (const float*)d_in[8];
  const float* cb2 = (const float*)d_in[9];
  const float* mW1 = (const float*)d_in[10];
  const float* mb1 = (const float*)d_in[11];
  const float* mW2 = (const float*)d_in[12];
  const float* mb2 = (const float*)d_in[13];
  const float* mW3 = (const float*)d_in[14];
  const float* mb3 = (const float*)d_in[15];
  float* out = (float*)d_out;

  char* p = (char*)d_ws;
  const size_t HB = (size_t)N_NODES * HIDDEN * sizeof(ushort);  // 25.6 MB
  ushort* h = (ushort*)p;      p += HB;
  ushort* t0 = (ushort*)p;     p += HB;
  ushort* Wtb = (ushort*)p;    p += (size_t)8 * 16384 * sizeof(ushort);
  int* cursor = (int*)p;       p += (size_t)N_NODES * sizeof(int);
  int* bins = (int*)p;         p += 64 * sizeof(int);
  int* slots = (int*)p;        p += (size_t)N_NODES * CAP * sizeof(int);
  int* perm = (int*)p;         p += (size_t)PADN * sizeof(int);

  (void)hipMemsetAsync(cursor, 0, ((size_t)N_NODES + 64) * sizeof(int), stream);  // cursor + bins
  prep_k<<<BUILD_BLKS + EMBED_BLKS + WT_BLKS, 256, 0, stream>>>(
      src, dst, cursor, slots, x, node_emb, h, cW1, cW2, Wtb);
  hist_k<<<PADN / 256, 256, 0, stream>>>(cursor, bins);
  scan_k<<<1, 64, 0, stream>>>(bins);
  scatter_k<<<PADN / 256, 256, 0, stream>>>(cursor, bins, perm);

  const int grid = PADN / 32;  // 3128 tiles, 2 waves each
  ushort* bufs[2] = {h, t0};
  for (int l = 0; l < 4; l++) {
    layer_k<<<grid, 128, 0, stream>>>(bufs[l & 1], cursor, slots, perm,
                                      Wtb + (size_t)(2 * l) * 16384,
                                      Wtb + (size_t)(2 * l + 1) * 16384,
                                      cb1 + (size_t)l * HIDDEN,
                                      cb2 + (size_t)l * HIDDEN,
                                      bufs[(l & 1) ^ 1]);
  }
  // after 4 layers output is back in h (bufs[0])
  poolmlp_k<<<NUM_GRAPHS, 256, 0, stream>>>(h, batch, mW1, mb1, mW2, mb2, mW3, mb3, out);
}

// Round 4
// 358.924 us; speedup vs baseline: 1.5704x; 1.0324x over previous
//
#include <hip/hip_runtime.h>

#define N_NODES 100000
#define N_EDGES 625000
#define HIDDEN 128
#define NUM_GRAPHS 512
#define CAP 40       // max in-degree capacity; Poisson(6.25) => P(deg>40) ~ e-43
#define PADN 100096  // multiple of 256

#define BUILD_BLKS 2443   // ceil(625000/256)
#define EMBED_BLKS 6250   // N_NODES*16/256
#define WT_BLKS 64        // 8 mats x 8 chunks

typedef unsigned int uint;
typedef unsigned short ushort;
typedef short v8s __attribute__((ext_vector_type(8)));
typedef float v16f __attribute__((ext_vector_type(16)));

__device__ __forceinline__ float b2f_lo(uint u) { return __uint_as_float(u << 16); }
__device__ __forceinline__ float b2f_hi(uint u) { return __uint_as_float(u & 0xffff0000u); }
__device__ __forceinline__ uint f2b(float f) {  // RNE f32 -> bf16 bits
  uint u = __float_as_uint(f);
  return (u + 0x7fffu + ((u >> 16) & 1u)) >> 16;
}

// ---------------- fused prep: build adjacency + embed + weight-quantize ----------------
__global__ __launch_bounds__(256) void prep_k(const int* __restrict__ src,
                                              const int* __restrict__ dst,
                                              int* __restrict__ cursor,
                                              int* __restrict__ slots,
                                              const int* __restrict__ x,
                                              const float* __restrict__ emb,
                                              ushort* __restrict__ h,
                                              const float* __restrict__ W1,
                                              const float* __restrict__ W2,
                                              ushort* __restrict__ Wt) {
  int blk = blockIdx.x;
  int tid = threadIdx.x;
  if (blk < BUILD_BLKS) {
    int e = blk * 256 + tid;
    if (e < N_EDGES) {
      int d = dst[e];
      int p = atomicAdd(&cursor[d], 1);
      if (p < CAP) slots[(size_t)d * CAP + p] = src[e];
    }
  } else if (blk < BUILD_BLKS + EMBED_BLKS) {
    int t = (blk - BUILD_BLKS) * 256 + tid;   // one 8-col chunk per thread
    int n = t >> 4;
    if (n < N_NODES) {
      int c = t & 15;
      const float4* e4 = (const float4*)(emb + (size_t)x[n] * HIDDEN + c * 8);
      float4 a = e4[0], b = e4[1];
      uint4 o;
      o.x = f2b(a.x) | (f2b(a.y) << 16);
      o.y = f2b(a.z) | (f2b(a.w) << 16);
      o.z = f2b(b.x) | (f2b(b.y) << 16);
      o.w = f2b(b.z) | (f2b(b.w) << 16);
      ((uint4*)h)[t] = o;
    }
  } else {
    int wb = blk - BUILD_BLKS - EMBED_BLKS;   // 0..63
    int mat = wb >> 3, chunk = wb & 7;
    const float* W = ((mat & 1) ? W2 : W1) + (size_t)(mat >> 1) * 16384;
    ushort* o = Wt + (size_t)mat * 16384;
#pragma unroll
    for (int jj = 0; jj < 8; jj++) {
      int idx = chunk * 2048 + tid + 256 * jj;  // coalesced read W[k][n]
      int k = idx >> 7, n = idx & 127;
      int c = n >> 5, l31 = n & 31;
      int ks = k >> 4, khalf = (k >> 3) & 1, e = k & 7;
      // fragment-ordered: slot s=c*8+ks, lane=khalf*32+l31, elem e
      o[(((c * 8 + ks) << 6) + (khalf << 5) + l31) * 8 + e] = (ushort)f2b(W[idx]);
    }
  }
}

// ---------------- degree-grouped permutation, two-level (LDS-aggregated) ----------------
__global__ __launch_bounds__(256) void hist_k(const int* __restrict__ cursor,
                                              int* __restrict__ bins) {
  __shared__ int lb[CAP + 1];
  int tid = threadIdx.x;
  if (tid <= CAP) lb[tid] = 0;
  __syncthreads();
  int n = blockIdx.x * 256 + tid;
  if (n < N_NODES) {
    int d = cursor[n]; if (d > CAP) d = CAP;
    atomicAdd(&lb[d], 1);                     // LDS atomic: cheap
  }
  __syncthreads();
  if (tid <= CAP && lb[tid] > 0) atomicAdd(&bins[tid], lb[tid]);  // fire-and-forget
}

__global__ __launch_bounds__(64) void scan_k(int* __restrict__ bins) {
  int i = threadIdx.x;
  int c = (i <= CAP) ? bins[i] : 0;
  int incl = c;
#pragma unroll
  for (int off = 1; off < 64; off <<= 1) {
    int t = __shfl_up(incl, off, 64);
    if (i >= off) incl += t;
  }
  if (i <= CAP) bins[i] = incl - c;           // exclusive prefix
}

// LPT dispatch: perm REVERSED (descending degree) so deg-40 blocks launch first.
__global__ __launch_bounds__(256) void scatter_k(const int* __restrict__ cursor,
                                                 int* __restrict__ bins,
                                                 int* __restrict__ perm) {
  __shared__ int lb[CAP + 1];
  __shared__ int lbase[CAP + 1];
  int tid = threadIdx.x;
  if (tid <= CAP) lb[tid] = 0;
  __syncthreads();
  int n = blockIdx.x * 256 + tid;
  int d = 0, rank = 0;
  bool real = (n < N_NODES);
  if (real) {
    d = cursor[n]; if (d > CAP) d = CAP;
    rank = atomicAdd(&lb[d], 1);
  }
  __syncthreads();
  if (tid <= CAP) {
    int c = lb[tid];
    lbase[tid] = c > 0 ? atomicAdd(&bins[tid], c) : 0;
  }
  __syncthreads();
  if (real) perm[(N_NODES - 1) - (lbase[d] + rank)] = n;   // descending degree
  else if (n < PADN) perm[n] = 0;
}

// ---------------- split layer, stage 1: agg (gather + sum + round) ----------------
// R14: gather decoupled from MFMA so registers don't cap concurrency.
// 8 rows/wave, 8 lanes/row (q = lane>>3 owns 16 cols = 2 uint4). Depth-4 row
// pipeline P0..P3 (4 x 8 VGPR). (256,5) -> 20 waves/CU (2.5x fused baseline);
// grid 12512 waves sustains it. Per load instr: 8 x 128B contiguous segments
// (vs 32 x 32B fused) -> half the TA transactions, full-line fetches.
// f32 add order = fused path (self first, then slot order) -> bit-identical t1.
union U { uint4 u; v8s s; };

__device__ __forceinline__ void loadrow2(uint4 dst[2], const uint4* __restrict__ rowp,
                                         int q) {
  dst[0] = rowp[q];
  dst[1] = rowp[q + 8];
}

__device__ __forceinline__ void accum2(const uint4 u[2], float acc[2][8]) {
#pragma unroll
  for (int ks = 0; ks < 2; ks++) {
    acc[ks][0] += b2f_lo(u[ks].x); acc[ks][1] += b2f_hi(u[ks].x);
    acc[ks][2] += b2f_lo(u[ks].y); acc[ks][3] += b2f_hi(u[ks].y);
    acc[ks][4] += b2f_lo(u[ks].z); acc[ks][5] += b2f_hi(u[ks].z);
    acc[ks][6] += b2f_lo(u[ks].w); acc[ks][7] += b2f_hi(u[ks].w);
  }
}

__global__ __launch_bounds__(256, 5) void agg_k(const ushort* __restrict__ hin,
                                                const int* __restrict__ cursor,
                                                const int* __restrict__ slots,
                                                const int* __restrict__ perm,
                                                ushort* __restrict__ t1) {
  int tid = threadIdx.x;
  int lane = tid & 63;
  int w = blockIdx.x * 4 + (tid >> 6);        // global wave id; 8 perm rows each
  int r8 = lane & 7;                          // row within wave
  int q = lane >> 3;                          // column eighth (16 cols)
  int pidx = w * 8 + r8;                      // perm index (< PADN by grid)
  bool valid = pidx < N_NODES;
  int prow = valid ? perm[pidx] : 0;
  int deg = valid ? cursor[prow] : 0;
  if (deg > CAP) deg = CAP;
  const int4* slv = (const int4*)(slots + (size_t)prow * CAP);  // chunks 0..9
  const uint4* base = (const uint4*)hin;      // 16 uint4 per 128-col row

  float acc[2][8];
#pragma unroll
  for (int ks = 0; ks < 2; ks++)
#pragma unroll
    for (int e = 0; e < 8; e++) acc[ks][e] = 0.f;

  uint4 P0[2], P1[2], P2[2], P3[2];
  int4 ck = slv[0];                           // slots 0..3
  int4 cn = slv[1];                           // slots 4..7

  loadrow2(P3, base + (size_t)prow * 16, q);                  // self
  if (deg > 0) loadrow2(P0, base + (size_t)ck.x * 16, q);     // row 0
  if (deg > 1) loadrow2(P1, base + (size_t)ck.y * 16, q);     // row 1
  if (deg > 2) loadrow2(P2, base + (size_t)ck.z * 16, q);     // row 2
  __builtin_amdgcn_sched_barrier(0);
  accum2(P3, acc);                                            // self first

  // invariant at loop head (j % 4 == 0): P0..P2 hold rows j..j+2 (where < deg);
  // ck covers slots j..j+3, cn covers j+4..j+7.
  int j = 0;
  while (j + 4 <= deg) {
    loadrow2(P3, base + (size_t)ck.w * 16, q);                // row j+3
    __builtin_amdgcn_sched_barrier(0);
    accum2(P0, acc);                                          // row j
    int ni = (j >> 2) + 2; if (ni > 9) ni = 9;                // clamp: stay in row
    int4 nx = slv[ni];
    if (j + 4 < deg) loadrow2(P0, base + (size_t)cn.x * 16, q);
    __builtin_amdgcn_sched_barrier(0);
    accum2(P1, acc);                                          // row j+1
    if (j + 5 < deg) loadrow2(P1, base + (size_t)cn.y * 16, q);
    __builtin_amdgcn_sched_barrier(0);
    accum2(P2, acc);                                          // row j+2
    if (j + 6 < deg) loadrow2(P2, base + (size_t)cn.z * 16, q);
    __builtin_amdgcn_sched_barrier(0);
    accum2(P3, acc);                                          // row j+3
    ck = cn; cn = nx;
    j += 4;
  }
  if (j < deg)     accum2(P0, acc);
  if (j + 1 < deg) accum2(P1, acc);
  if (j + 2 < deg) accum2(P2, acc);

  if (valid) {
    uint4 o0, o1;
    o0.x = f2b(acc[0][0]) | (f2b(acc[0][1]) << 16);
    o0.y = f2b(acc[0][2]) | (f2b(acc[0][3]) << 16);
    o0.z = f2b(acc[0][4]) | (f2b(acc[0][5]) << 16);
    o0.w = f2b(acc[0][6]) | (f2b(acc[0][7]) << 16);
    o1.x = f2b(acc[1][0]) | (f2b(acc[1][1]) << 16);
    o1.y = f2b(acc[1][2]) | (f2b(acc[1][3]) << 16);
    o1.z = f2b(acc[1][4]) | (f2b(acc[1][5]) << 16);
    o1.w = f2b(acc[1][6]) | (f2b(acc[1][7]) << 16);
    uint4* orow = (uint4*)(t1 + (size_t)prow * HIDDEN);
    orow[q] = o0;
    orow[q + 8] = o1;
  }
}

// ---------------- split layer, stage 2: dense 2-GEMM, in-place on t ----------------
// Natural row order (no perm/slots): coalesced reads, coalesced writes.
// In-place safe: one wave per block; each row read only by its own block, and
// the wave's 8 loads retire (s_waitcnt before MFMA) before any store issues.
__global__ __launch_bounds__(64, 3) void gemm_k(ushort* __restrict__ t,
                                                const ushort* __restrict__ W1f,
                                                const ushort* __restrict__ W2f,
                                                const float* __restrict__ b1,
                                                const float* __restrict__ b2) {
  int lane = threadIdx.x;                     // 0..63
  int l31 = lane & 31;
  int khalf = lane >> 5;
  int rb = blockIdx.x * 32;                   // 3125 * 32 == 100000 exactly

  const uint4* rowp = (const uint4*)t + (size_t)(rb + l31) * 16;
  U afr[8];
#pragma unroll
  for (int ks = 0; ks < 8; ks++) afr[ks].u = rowp[khalf + 2 * ks];

  // ---- GEMM1 (flipped): z^T = W1^T-as-A @ agg-as-B; lane = node row ----
  const uint4* W1v = (const uint4*)W1f;       // frag-ordered: slot*64 + lane
  v16f acc1[4] = {};
#pragma unroll
  for (int c = 0; c < 4; c++)
#pragma unroll
    for (int ks = 0; ks < 8; ks++) {
      U b; b.u = W1v[((c * 8 + ks) << 6) + lane];
      acc1[c] = __builtin_amdgcn_mfma_f32_32x32x16_bf16(b.s, afr[ks].s, acc1[c], 0, 0, 0);
    }

  // bias + relu + pack: lane holds z[r=l31][k'], k' = 32c + (reg&3) + 8*(reg>>2) + 4*khalf
  uint u[4][4][2];
#pragma unroll
  for (int c = 0; c < 4; c++)
#pragma unroll
    for (int b = 0; b < 4; b++)
#pragma unroll
      for (int ap = 0; ap < 2; ap++) {
        int r0 = 2 * ap + 4 * b, r1 = r0 + 1;
        float v0 = fmaxf(acc1[c][r0] + b1[c * 32 + 2 * ap + 8 * b + 4 * khalf], 0.f);
        float v1 = fmaxf(acc1[c][r1] + b1[c * 32 + 2 * ap + 1 + 8 * b + 4 * khalf], 0.f);
        u[c][b][ap] = f2b(v0) | (f2b(v1) << 16);
      }

  uint got[4][2][2];
#pragma unroll
  for (int c = 0; c < 4; c++)
#pragma unroll
    for (int bh = 0; bh < 2; bh++)
#pragma unroll
      for (int ap = 0; ap < 2; ap++) {
        uint send = khalf ? u[c][2 * bh][ap] : u[c][2 * bh + 1][ap];
        got[c][bh][ap] = __shfl_xor(send, 32, 64);
      }

  U az[8];
#pragma unroll
  for (int ks = 0; ks < 8; ks++) {
    uint o0 = khalf ? u[ks >> 1][2 * (ks & 1) + 1][0] : u[ks >> 1][2 * (ks & 1)][0];
    uint o1 = khalf ? u[ks >> 1][2 * (ks & 1) + 1][1] : u[ks >> 1][2 * (ks & 1)][1];
    uint g0 = got[ks >> 1][ks & 1][0];
    uint g1 = got[ks >> 1][ks & 1][1];
    az[ks].u.x = khalf ? g0 : o0;
    az[ks].u.y = khalf ? g1 : o1;
    az[ks].u.z = khalf ? o0 : g0;
    az[ks].u.w = khalf ? o1 : g1;
  }

  // ---- GEMM2 (normal): h_out = z @ W2 + b2 ----
  const uint4* W2v = (const uint4*)W2f;
  v16f acc2[4] = {};
#pragma unroll
  for (int c = 0; c < 4; c++)
#pragma unroll
    for (int ks = 0; ks < 8; ks++) {
      U b; b.u = W2v[((c * 8 + ks) << 6) + lane];
      acc2[c] = __builtin_amdgcn_mfma_f32_32x32x16_bf16(az[ks].s, b.s, acc2[c], 0, 0, 0);
    }

  float bv2[4];
#pragma unroll
  for (int c = 0; c < 4; c++) bv2[c] = b2[c * 32 + l31];
#pragma unroll
  for (int c = 0; c < 4; c++) {
    int col = c * 32 + l31;
#pragma unroll
    for (int r = 0; r < 16; r++) {
      int m = (r & 3) + 8 * (r >> 2) + 4 * khalf;
      t[(size_t)(rb + m) * HIDDEN + col] = (ushort)f2b(acc2[c][r] + bv2[c]);
    }
  }
}

// ---------------- fused pool+MLP: g = segsum(h); out = mlp(g) ----------------
__global__ __launch_bounds__(256) void poolmlp_k(const ushort* __restrict__ h,
                                                 const int* __restrict__ batch,
                                                 const float* __restrict__ W1, const float* __restrict__ b1,
                                                 const float* __restrict__ W2, const float* __restrict__ b2,
                                                 const float* __restrict__ W3, const float* __restrict__ b3,
                                                 float* __restrict__ out) {
  __shared__ int se[2];
  __shared__ float red[16][16][8];
  __shared__ float gl[128];
  __shared__ float r2[64];
  __shared__ float r3[32];
  int gi = blockIdx.x, tid = threadIdx.x;
  if (tid < 2) {
    int target = gi + tid;
    int lo = 0, hi = N_NODES;
    while (lo < hi) {
      int mid = (lo + hi) >> 1;
      if (batch[mid] < target) lo = mid + 1; else hi = mid;
    }
    se[tid] = lo;
  }
  __syncthreads();
  int start = se[0], end = se[1];
  int cg = tid & 15, rg = tid >> 4;
  float acc[8] = {0.f, 0.f, 0.f, 0.f, 0.f, 0.f, 0.f, 0.f};
  for (int r = start + rg; r < end; r += 16) {
    uint4 v = ((const uint4*)h)[r * 16 + cg];
    acc[0] += b2f_lo(v.x); acc[1] += b2f_hi(v.x);
    acc[2] += b2f_lo(v.y); acc[3] += b2f_hi(v.y);
    acc[4] += b2f_lo(v.z); acc[5] += b2f_hi(v.z);
    acc[6] += b2f_lo(v.w); acc[7] += b2f_hi(v.w);
  }
#pragma unroll
  for (int j = 0; j < 8; j++) red[rg][cg][j] = acc[j];
  __syncthreads();
  if (rg == 0) {
    float s[8];
#pragma unroll
    for (int j = 0; j < 8; j++) s[j] = red[0][cg][j];
#pragma unroll
    for (int i = 1; i < 16; i++)
#pragma unroll
      for (int j = 0; j < 8; j++) s[j] += red[i][cg][j];
#pragma unroll
    for (int j = 0; j < 8; j++) gl[cg * 8 + j] = s[j];
  }
  __syncthreads();
  if (tid < 64) {
    float s = b1[tid];
    for (int k = 0; k < 128; k++) s = fmaf(gl[k], W1[k * 64 + tid], s);
    r2[tid] = fmaxf(s, 0.f);
  }
  __syncthreads();
  if (tid < 32) {
    float s2 = b2[tid];
    for (int k = 0; k < 64; k++) s2 = fmaf(r2[k], W2[k * 32 + tid], s2);
    r3[tid] = fmaxf(s2, 0.f);
  }
  __syncthreads();
  if (tid < 64) {
    float pv = (tid < 32) ? r3[tid] * W3[tid] : 0.f;
#pragma unroll
    for (int off = 32; off > 0; off >>= 1) pv += __shfl_down(pv, off);
    if (tid == 0) out[gi] = pv + b3[0];
  }
}

extern "C" void kernel_launch(void* const* d_in, const int* in_sizes, int n_in,
                              void* d_out, int out_size, void* d_ws, size_t ws_size,
                              hipStream_t stream) {
  const int* x = (const int*)d_in[0];
  const int* src = (const int*)d_in[1];
  const int* dst = src + N_EDGES;
  const int* batch = (const int*)d_in[3];
  const float* node_emb = (const float*)d_in[4];
  const float* cW1 = (const float*)d_in[6];
  const float* cb1 = (const float*)d_in[7];
  const float* cW2 = (const float*)d_in[8];
  const float* cb2 = (const float*)d_in[9];
  const float* mW1 = (const float*)d_in[10];
  const float* mb1 = (const float*)d_in[11];
  const float* mW2 = (const float*)d_in[12];
  const float* mb2 = (const float*)d_in[13];
  const float* mW3 = (const float*)d_in[14];
  const float* mb3 = (const float*)d_in[15];
  float* out = (float*)d_out;

  char* p = (char*)d_ws;
  const size_t HB = (size_t)N_NODES * HIDDEN * sizeof(ushort);  // 25.6 MB
  ushort* h = (ushort*)p;      p += HB;
  ushort* t0 = (ushort*)p;     p += HB;
  ushort* Wtb = (ushort*)p;    p += (size_t)8 * 16384 * sizeof(ushort);
  int* cursor = (int*)p;       p += (size_t)N_NODES * sizeof(int);
  int* bins = (int*)p;         p += 64 * sizeof(int);
  int* slots = (int*)p;        p += (size_t)N_NODES * CAP * sizeof(int);
  int* perm = (int*)p;         p += (size_t)PADN * sizeof(int);

  (void)hipMemsetAsync(cursor, 0, ((size_t)N_NODES + 64) * sizeof(int), stream);  // cursor + bins
  prep_k<<<BUILD_BLKS + EMBED_BLKS + WT_BLKS, 256, 0, stream>>>(
      src, dst, cursor, slots, x, node_emb, h, cW1, cW2, Wtb);
  hist_k<<<PADN / 256, 256, 0, stream>>>(cursor, bins);
  scan_k<<<1, 64, 0, stream>>>(bins);
  scatter_k<<<PADN / 256, 256, 0, stream>>>(cursor, bins, perm);

  ushort* bufs[2] = {h, t0};
  for (int l = 0; l < 4; l++) {
    ushort* in = bufs[l & 1];
    ushort* tmp = bufs[(l & 1) ^ 1];
    agg_k<<<PADN / 32, 256, 0, stream>>>(in, cursor, slots, perm, tmp);
    gemm_k<<<N_NODES / 32, 64, 0, stream>>>(tmp,
                                            Wtb + (size_t)(2 * l) * 16384,
                                            Wtb + (size_t)(2 * l + 1) * 16384,
                                            cb1 + (size_t)l * HIDDEN,
                                            cb2 + (size_t)l * HIDDEN);
  }
  // after 4 layers output is back in h (bufs[0])
  poolmlp_k<<<NUM_GRAPHS, 256, 0, stream>>>(h, batch, mW1, mb1, mW2, mb2, mW3, mb3, out);
}